// Round 2
// baseline (225.580 us; speedup 1.0000x reference)
//
#include <hip/hip_runtime.h>
#include <stdint.h>

// BertSelfAttentionWithRelation  B=4 L=512 H=12 D=64 HIDDEN=768
// Round 1: split attn_mid -> k_rel1 (relk+softmax) + k_rel2 (relv), occupancy-
// and pipeline-focused. global_load_lds staging with pre-swizzled source.
//   ws layout (bytes):
//     hb   bf16 hidden        [2048][768]           3,145,728
//     wt   bf16 W^T concat    [2304][768]           3,538,944
//     qbf  bf16 q [B][H][L][D]                      3,145,728
//     kbf  bf16 k [B][H][L][D]                      3,145,728
//     vbt  bf16 v^T [B][H][D][L]                    3,145,728
//     S    f32 content scores [B][H][L][L]         50,331,648
//     pbf  bf16 probs [B][H][L][L]                 25,165,824
//     crel f32 relation-ctx   [B][L][768]           6,291,456
//   total ~97.9 MB

typedef __attribute__((ext_vector_type(8))) short bf16x8;
typedef __attribute__((ext_vector_type(4))) float f32x4;
typedef __attribute__((ext_vector_type(4))) unsigned int u32x4;

__device__ __forceinline__ unsigned short f2bf(float f) {
  union { float f; unsigned int u; } v; v.f = f;
  unsigned int r = v.u + 0x7fffu + ((v.u >> 16) & 1u);
  return (unsigned short)(r >> 16);
}
__device__ __forceinline__ float bf2f(unsigned short s) {
  union { unsigned int u; float f; } v; v.u = ((unsigned int)s) << 16;
  return v.f;
}
__device__ __forceinline__ void gload_lds16(const void* g, void* l) {
  __builtin_amdgcn_global_load_lds((const __attribute__((address_space(1))) void*)g,
                                   (__attribute__((address_space(3))) void*)l, 16, 0, 0);
}

// ---------------- K0a: hidden fp32 -> bf16 ----------------
__global__ void k_cvt_hidden(const float* __restrict__ x, unsigned short* __restrict__ y) {
  int i = blockIdx.x * 256 + threadIdx.x;        // 1536*256 = 393216 float4s exactly
  float4 v = reinterpret_cast<const float4*>(x)[i];
  ushort4 o;
  o.x = f2bf(v.x); o.y = f2bf(v.y); o.z = f2bf(v.z); o.w = f2bf(v.w);
  reinterpret_cast<ushort4*>(y)[i] = o;
}

// ---------------- K0b: W -> W^T concat bf16  wt[n][k] = W[k][n] ----------------
__global__ void k_transp_w(const float* __restrict__ Wq, const float* __restrict__ Wk,
                           const float* __restrict__ Wv, unsigned short* __restrict__ wt) {
  __shared__ float t[64][65];
  const int kt = blockIdx.x, nt = blockIdx.y, wsel = blockIdx.z;
  const float* W = wsel == 0 ? Wq : (wsel == 1 ? Wk : Wv);
  const int lx = threadIdx.x & 63, ly = threadIdx.x >> 6;
  for (int i = 0; i < 64; i += 4)
    t[ly + i][lx] = W[(size_t)(kt * 64 + ly + i) * 768 + nt * 64 + lx];
  __syncthreads();
  for (int i = 0; i < 64; i += 4) {
    int r = ly + i;
    wt[((size_t)wsel * 768 + nt * 64 + r) * 768 + kt * 64 + lx] = f2bf(t[lx][r]);
  }
}

// ---------------- K1: fused QKV GEMM (bf16 MFMA) ----------------
__global__ __launch_bounds__(256) void k_qkv_gemm(
    const unsigned short* __restrict__ A,   // [2048][768] bf16
    const unsigned short* __restrict__ Bt,  // [2304][768] bf16 (row n, col k)
    const float* __restrict__ bq, const float* __restrict__ bk, const float* __restrict__ bv,
    unsigned short* __restrict__ qbf,       // [B][H][L][D]
    unsigned short* __restrict__ kbf,       // [B][H][L][D]
    unsigned short* __restrict__ vbt) {     // [B][H][D][L]
  __shared__ __align__(16) unsigned short lA[64 * 64];
  __shared__ __align__(16) unsigned short lB[64 * 64];
  const int tid = threadIdx.x, lane = tid & 63, w = tid >> 6;
  const int m0 = blockIdx.x * 64, n0 = blockIdx.y * 64;
  const int wm = (w >> 1) * 32, wn = (w & 1) * 32;
  f32x4 acc[2][2] = {};

  for (int kt = 0; kt < 12; ++kt) {
    __syncthreads();
#pragma unroll
    for (int i = 0; i < 2; ++i) {
      int e16 = i * 256 + tid;          // 16B unit, 0..511 (64 rows x 128B)
      int row = e16 >> 3;
      int kb = (e16 & 7) * 16;
      int dst = row * 128 + (kb ^ ((row & 7) << 4));   // XOR swizzle
      u32x4 va = *(const u32x4*)((const char*)A + (size_t)(m0 + row) * 1536 + kt * 128 + kb);
      *(u32x4*)((char*)lA + dst) = va;
      u32x4 vb = *(const u32x4*)((const char*)Bt + (size_t)(n0 + row) * 1536 + kt * 128 + kb);
      *(u32x4*)((char*)lB + dst) = vb;
    }
    __syncthreads();
#pragma unroll
    for (int ks = 0; ks < 2; ++ks) {
      bf16x8 fa[2], fb[2];
      const int kbyte = (ks * 32 + (lane >> 4) * 8) * 2;
#pragma unroll
      for (int mi = 0; mi < 2; ++mi) {
        int row = wm + mi * 16 + (lane & 15);
        fa[mi] = *(const bf16x8*)((const char*)lA + row * 128 + (kbyte ^ ((row & 7) << 4)));
      }
#pragma unroll
      for (int ni = 0; ni < 2; ++ni) {
        int row = wn + ni * 16 + (lane & 15);
        fb[ni] = *(const bf16x8*)((const char*)lB + row * 128 + (kbyte ^ ((row & 7) << 4)));
      }
#pragma unroll
      for (int mi = 0; mi < 2; ++mi)
#pragma unroll
        for (int ni = 0; ni < 2; ++ni)
          acc[mi][ni] = __builtin_amdgcn_mfma_f32_16x16x32_bf16(fa[mi], fb[ni], acc[mi][ni], 0, 0, 0);
    }
  }
#pragma unroll
  for (int mi = 0; mi < 2; ++mi)
#pragma unroll
    for (int ni = 0; ni < 2; ++ni) {
      int gn = n0 + wn + ni * 16 + (lane & 15);
      float bias = (gn < 768) ? bq[gn] : (gn < 1536 ? bk[gn - 768] : bv[gn - 1536]);
#pragma unroll
      for (int r = 0; r < 4; ++r) {
        int gm = m0 + wm + mi * 16 + ((lane >> 4) << 2) + r;
        float val = acc[mi][ni][r] + bias;
        int b = gm >> 9, l = gm & 511;
        int d = gn & 63;
        if (gn < 768) {
          int h = gn >> 6;
          qbf[(((size_t)(b * 12 + h)) * 512 + l) * 64 + d] = f2bf(val);
        } else if (gn < 1536) {
          int h = (gn - 768) >> 6;
          kbf[(((size_t)(b * 12 + h)) * 512 + l) * 64 + d] = f2bf(val);
        } else {
          int h = (gn - 1536) >> 6;
          vbt[(((size_t)(b * 12 + h)) * 64 + d) * 512 + l] = f2bf(val);
        }
      }
    }
}

// ---------------- K2a: content scores S = q.k^T per (b,h) via MFMA ----------------
__global__ __launch_bounds__(256) void k_scores(
    const unsigned short* __restrict__ qbf, const unsigned short* __restrict__ kbf,
    float* __restrict__ S) {
  __shared__ __align__(16) unsigned short lQ[64 * 64];
  __shared__ __align__(16) unsigned short lK[64 * 64];
  const int tid = threadIdx.x, lane = tid & 63, w = tid >> 6;
  const int mt = blockIdx.x, lt = blockIdx.y, bh = blockIdx.z;
  const int wm = (w >> 1) * 32, wn = (w & 1) * 32;
  f32x4 acc[2][2] = {};
#pragma unroll
  for (int i = 0; i < 2; ++i) {
    int e16 = i * 256 + tid;
    int row = e16 >> 3;
    int kb = (e16 & 7) * 16;
    int dst = row * 128 + (kb ^ ((row & 7) << 4));
    u32x4 vq = *(const u32x4*)((const char*)qbf + ((size_t)bh * 512 + lt * 64 + row) * 128 + kb);
    *(u32x4*)((char*)lQ + dst) = vq;
    u32x4 vk = *(const u32x4*)((const char*)kbf + ((size_t)bh * 512 + mt * 64 + row) * 128 + kb);
    *(u32x4*)((char*)lK + dst) = vk;
  }
  __syncthreads();
#pragma unroll
  for (int ks = 0; ks < 2; ++ks) {
    bf16x8 fa[2], fb[2];
    const int kbyte = (ks * 32 + (lane >> 4) * 8) * 2;
#pragma unroll
    for (int mi = 0; mi < 2; ++mi) {
      int row = wm + mi * 16 + (lane & 15);
      fa[mi] = *(const bf16x8*)((const char*)lQ + row * 128 + (kbyte ^ ((row & 7) << 4)));
    }
#pragma unroll
    for (int ni = 0; ni < 2; ++ni) {
      int row = wn + ni * 16 + (lane & 15);
      fb[ni] = *(const bf16x8*)((const char*)lK + row * 128 + (kbyte ^ ((row & 7) << 4)));
    }
#pragma unroll
    for (int mi = 0; mi < 2; ++mi)
#pragma unroll
      for (int ni = 0; ni < 2; ++ni)
        acc[mi][ni] = __builtin_amdgcn_mfma_f32_16x16x32_bf16(fa[mi], fb[ni], acc[mi][ni], 0, 0, 0);
  }
#pragma unroll
  for (int mi = 0; mi < 2; ++mi)
#pragma unroll
    for (int ni = 0; ni < 2; ++ni) {
      int gm = mt * 64 + wn + ni * 16 + (lane & 15);
#pragma unroll
      for (int r = 0; r < 4; ++r) {
        int gl = lt * 64 + wm + mi * 16 + ((lane >> 4) << 2) + r;
        S[(size_t)bh * 262144 + (size_t)gl * 512 + gm] = acc[mi][ni][r];
      }
    }
}

// ---------------- K2b: relation-K scores + content + softmax -> pbf ----------------
// one block per (b,l); 4 waves; wave owns 3 heads; lane owns r within 64-tile
__global__ __launch_bounds__(256) void k_rel1(
    const unsigned short* __restrict__ qbf,
    const float* __restrict__ relk,   // [B][L][L][D]  (b, l, r, d)
    const float* __restrict__ S,
    unsigned short* __restrict__ pbf) {
  __shared__ __align__(16) float qs[12 * 64];   // 3 KB
  __shared__ __align__(16) float rk[64 * 64];   // 16 KB, XOR-swizzled rows
  const int tid = threadIdx.x, lane = tid & 63, w = tid >> 6;
  const int bl = blockIdx.x;
  const int b = bl >> 9, l = bl & 511;

  for (int i = tid; i < 768; i += 256) {
    int h = i >> 6, d = i & 63;
    qs[i] = bf2f(qbf[(((size_t)(b * 12 + h)) * 512 + l) * 64 + d]);
  }

  float acc[3][8];
#pragma unroll
  for (int hh = 0; hh < 3; ++hh)
#pragma unroll
    for (int j = 0; j < 8; ++j) acc[hh][j] = 0.f;

  const char* relk_base = (const char*)relk + (size_t)bl * 131072;
#pragma unroll
  for (int t8 = 0; t8 < 8; ++t8) {
    __syncthreads();   // previous tile's readers done
    // stage 16KB tile via global_load_lds, pre-swizzled global source:
    // physical LDS slot (row, x') holds global[row*256 + (x'*16 ^ ((row&7)<<4))]
    {
      const char* gbase = relk_base + t8 * 16384;
#pragma unroll
      for (int i = 0; i < 4; ++i) {
        int slot = i * 256 + tid;           // linear 16B slot (lane-ordered per wave)
        int row = slot >> 4, x = slot & 15;
        const void* src = gbase + row * 256 + ((x * 16) ^ ((row & 7) << 4));
        gload_lds16(src, (char*)rk + (size_t)(i * 256 + w * 64) * 16);  // wave-uniform base
      }
    }
    __syncthreads();   // loads drained (compiler emits vmcnt(0) before barrier)
    // lane owns r = t8*64+lane; wave owns heads 3w..3w+2
#pragma unroll 4
    for (int dc = 0; dc < 16; ++dc) {
      f32x4 rv = *(const f32x4*)((const char*)rk + lane * 256 + ((dc * 16) ^ ((lane & 7) << 4)));
#pragma unroll
      for (int hh = 0; hh < 3; ++hh) {
        f32x4 q4 = *(const f32x4*)&qs[(w * 3 + hh) * 64 + dc * 4];
        acc[hh][t8] += rv.x * q4.x + rv.y * q4.y + rv.z * q4.z + rv.w * q4.w;
      }
    }
  }

  // content add, scale, softmax (row h lives on one wave), write probs bf16
#pragma unroll
  for (int hh = 0; hh < 3; ++hh) {
    int h = w * 3 + hh;
    size_t srow = (((size_t)(b * 12 + h)) * 512 + l) * 512;
    float mx = -1e30f;
#pragma unroll
    for (int j = 0; j < 8; ++j) {
      float s = (acc[hh][j] + S[srow + j * 64 + lane]) * 0.125f;
      acc[hh][j] = s;
      mx = fmaxf(mx, s);
    }
#pragma unroll
    for (int off = 32; off; off >>= 1) mx = fmaxf(mx, __shfl_xor(mx, off));
    float sm = 0.f;
#pragma unroll
    for (int j = 0; j < 8; ++j) { acc[hh][j] = __expf(acc[hh][j] - mx); sm += acc[hh][j]; }
#pragma unroll
    for (int off = 32; off; off >>= 1) sm += __shfl_xor(sm, off);
    float inv = 1.f / sm;
#pragma unroll
    for (int j = 0; j < 8; ++j)
      pbf[srow + j * 64 + lane] = f2bf(acc[hh][j] * inv);
  }
}

// ---------------- K2c: relation-V context, per (b,l) ----------------
// 4 waves; wave w handles r in [w*128, w*128+128); lane owns d; all 12 heads.
__global__ __launch_bounds__(256) void k_rel2(
    const unsigned short* __restrict__ pbf,   // [B][H][L][R] bf16
    const float* __restrict__ relv,           // [B][R][L][D]
    float* __restrict__ crel) {               // [B][L][768]
  __shared__ __align__(16) float red[4][12][64];   // 12 KB
  const int tid = threadIdx.x, lane = tid & 63, w = tid >> 6;
  const int bl = blockIdx.x;
  const int b = bl >> 9, l = bl & 511;

  float acc[12];
#pragma unroll
  for (int h = 0; h < 12; ++h) acc[h] = 0.f;

  const float* vbase = relv + ((size_t)b * 512 * 512 + (size_t)l) * 64 + lane;  // + r*32768
  const unsigned short* pb0 = pbf + ((size_t)b * 12 * 512 + l) * 512;           // + h*262144 + r

#pragma unroll 2
  for (int rc = 0; rc < 32; ++rc) {
    int r0 = w * 128 + rc * 4;
    float v0 = vbase[(size_t)(r0 + 0) * 32768];
    float v1 = vbase[(size_t)(r0 + 1) * 32768];
    float v2 = vbase[(size_t)(r0 + 2) * 32768];
    float v3 = vbase[(size_t)(r0 + 3) * 32768];
#pragma unroll
    for (int h = 0; h < 12; ++h) {
      ushort4 p4 = *(const ushort4*)(pb0 + (size_t)h * 262144 + r0);  // 8B wave-uniform broadcast
      acc[h] += bf2f(p4.x) * v0 + bf2f(p4.y) * v1 + bf2f(p4.z) * v2 + bf2f(p4.w) * v3;
    }
  }

#pragma unroll
  for (int h = 0; h < 12; ++h) red[w][h][lane] = acc[h];
  __syncthreads();
  for (int i = tid; i < 768; i += 256) {
    int h = i >> 6, d = i & 63;
    crel[(size_t)bl * 768 + i] =
        red[0][h][d] + red[1][h][d] + red[2][h][d] + red[3][h][d];
  }
}

// ---------------- K3: ctx = P@V per (b,h) via MFMA, + crel, write out ----------------
__global__ __launch_bounds__(256) void k_pv(
    const unsigned short* __restrict__ pbf,   // [B][H][L][M]
    const unsigned short* __restrict__ vbt,   // [B][H][D][M]
    const float* __restrict__ crel,
    float* __restrict__ out) {
  __shared__ __align__(16) unsigned short lP[64 * 64];
  __shared__ __align__(16) unsigned short lV[64 * 64];
  const int tid = threadIdx.x, lane = tid & 63, w = tid >> 6;
  const int lt = blockIdx.x, bh = blockIdx.y;
  const int b = bh / 12, h = bh % 12;
  const int wm = (w >> 1) * 32, wn = (w & 1) * 32;
  f32x4 acc[2][2] = {};
  const char* pbase = (const char*)pbf + ((size_t)bh * 512 + lt * 64) * 1024;
  const char* vbase = (const char*)vbt + (size_t)bh * 64 * 1024;
  for (int kt = 0; kt < 8; ++kt) {
    __syncthreads();
#pragma unroll
    for (int i = 0; i < 2; ++i) {
      int e16 = i * 256 + tid;
      int row = e16 >> 3;
      int kb = (e16 & 7) * 16;
      int dst = row * 128 + (kb ^ ((row & 7) << 4));
      u32x4 vp = *(const u32x4*)(pbase + (size_t)row * 1024 + kt * 128 + kb);
      *(u32x4*)((char*)lP + dst) = vp;
      u32x4 vv = *(const u32x4*)(vbase + (size_t)row * 1024 + kt * 128 + kb);
      *(u32x4*)((char*)lV + dst) = vv;
    }
    __syncthreads();
#pragma unroll
    for (int ks = 0; ks < 2; ++ks) {
      bf16x8 fa[2], fb[2];
      const int kbyte = (ks * 32 + (lane >> 4) * 8) * 2;
#pragma unroll
      for (int mi = 0; mi < 2; ++mi) {
        int row = wm + mi * 16 + (lane & 15);
        fa[mi] = *(const bf16x8*)((const char*)lP + row * 128 + (kbyte ^ ((row & 7) << 4)));
      }
#pragma unroll
      for (int ni = 0; ni < 2; ++ni) {
        int row = wn + ni * 16 + (lane & 15);
        fb[ni] = *(const bf16x8*)((const char*)lV + row * 128 + (kbyte ^ ((row & 7) << 4)));
      }
#pragma unroll
      for (int mi = 0; mi < 2; ++mi)
#pragma unroll
        for (int ni = 0; ni < 2; ++ni)
          acc[mi][ni] = __builtin_amdgcn_mfma_f32_16x16x32_bf16(fa[mi], fb[ni], acc[mi][ni], 0, 0, 0);
    }
  }
#pragma unroll
  for (int mi = 0; mi < 2; ++mi)
#pragma unroll
    for (int ni = 0; ni < 2; ++ni) {
      int gd = wn + ni * 16 + (lane & 15);
#pragma unroll
      for (int r = 0; r < 4; ++r) {
        int gl = lt * 64 + wm + mi * 16 + ((lane >> 4) << 2) + r;
        size_t o = ((size_t)b * 512 + gl) * 768 + h * 64 + gd;
        out[o] = acc[mi][ni][r] + crel[o];
      }
    }
}

extern "C" void kernel_launch(void* const* d_in, const int* in_sizes, int n_in,
                              void* d_out, int out_size, void* d_ws, size_t ws_size,
                              hipStream_t stream) {
  (void)in_sizes; (void)n_in; (void)out_size; (void)ws_size;
  const float* hidden = (const float*)d_in[0];
  const float* relk   = (const float*)d_in[1];
  const float* relv   = (const float*)d_in[2];
  const float* Wq     = (const float*)d_in[3];
  const float* bq     = (const float*)d_in[4];
  const float* Wk     = (const float*)d_in[5];
  const float* bk     = (const float*)d_in[6];
  const float* Wv     = (const float*)d_in[7];
  const float* bv     = (const float*)d_in[8];
  float* out = (float*)d_out;
  char* ws = (char*)d_ws;

  unsigned short* hb  = (unsigned short*)(ws);
  unsigned short* wt  = (unsigned short*)(ws + 3145728);
  unsigned short* qbf = (unsigned short*)(ws + 6684672);
  unsigned short* kbf = (unsigned short*)(ws + 9830400);
  unsigned short* vbt = (unsigned short*)(ws + 12976128);
  float*          S   = (float*)(ws + 16121856);
  unsigned short* pbf = (unsigned short*)(ws + 66453504);
  float*          cr  = (float*)(ws + 91619328);
  // end: 97,910,784 bytes

  k_cvt_hidden<<<1536, 256, 0, stream>>>(hidden, hb);
  k_transp_w<<<dim3(12, 12, 3), 256, 0, stream>>>(Wq, Wk, Wv, wt);
  k_qkv_gemm<<<dim3(32, 36), 256, 0, stream>>>(hb, wt, bq, bk, bv, qbf, kbf, vbt);
  k_scores<<<dim3(8, 8, 48), 256, 0, stream>>>(qbf, kbf, S);
  k_rel1<<<2048, 256, 0, stream>>>(qbf, relk, S, pbf);
  k_rel2<<<2048, 256, 0, stream>>>(pbf, relv, cr);
  k_pv<<<dim3(8, 48), 256, 0, stream>>>(pbf, vbt, cr, out);
}

// Round 3
// 200.052 us; speedup vs baseline: 1.1276x; 1.1276x over previous
//
#include <hip/hip_runtime.h>
#include <stdint.h>

// BertSelfAttentionWithRelation  B=4 L=512 H=12 D=64 HIDDEN=768
// Round 3: fused k_rel (relk-scores + softmax + relv-context in one kernel):
//   - phase A: relk streamed via double-buffered global_load_lds (prefetch
//     tile t+1 while computing tile t) -> no drain-before-compute stall
//   - phase B: in-register softmax (wave owns 3 heads), probs -> LDS bf16 + pbf
//   - phase C: relv streamed with 8 row-loads in flight/wave, probs broadcast
//     from LDS (no global p re-read)
//   ws layout (bytes):
//     hb   bf16 hidden        [2048][768]           3,145,728
//     wt   bf16 W^T concat    [2304][768]           3,538,944
//     qbf  bf16 q [B][H][L][D]                      3,145,728
//     kbf  bf16 k [B][H][L][D]                      3,145,728
//     vbt  bf16 v^T [B][H][D][L]                    3,145,728
//     S    f32 content scores [B][H][L][L]         50,331,648
//     pbf  bf16 probs [B][H][L][L]                 25,165,824
//     crel f32 relation-ctx   [B][L][768]           6,291,456
//   total ~97.9 MB

typedef __attribute__((ext_vector_type(8))) short bf16x8;
typedef __attribute__((ext_vector_type(4))) float f32x4;
typedef __attribute__((ext_vector_type(4))) unsigned int u32x4;

__device__ __forceinline__ unsigned short f2bf(float f) {
  union { float f; unsigned int u; } v; v.f = f;
  unsigned int r = v.u + 0x7fffu + ((v.u >> 16) & 1u);
  return (unsigned short)(r >> 16);
}
__device__ __forceinline__ float bf2f(unsigned short s) {
  union { unsigned int u; float f; } v; v.u = ((unsigned int)s) << 16;
  return v.f;
}
__device__ __forceinline__ void gload_lds16(const void* g, void* l) {
  __builtin_amdgcn_global_load_lds((const __attribute__((address_space(1))) void*)g,
                                   (__attribute__((address_space(3))) void*)l, 16, 0, 0);
}

// ---------------- K0a: hidden fp32 -> bf16 ----------------
__global__ void k_cvt_hidden(const float* __restrict__ x, unsigned short* __restrict__ y) {
  int i = blockIdx.x * 256 + threadIdx.x;        // 1536*256 = 393216 float4s exactly
  float4 v = reinterpret_cast<const float4*>(x)[i];
  ushort4 o;
  o.x = f2bf(v.x); o.y = f2bf(v.y); o.z = f2bf(v.z); o.w = f2bf(v.w);
  reinterpret_cast<ushort4*>(y)[i] = o;
}

// ---------------- K0b: W -> W^T concat bf16  wt[n][k] = W[k][n] ----------------
__global__ void k_transp_w(const float* __restrict__ Wq, const float* __restrict__ Wk,
                           const float* __restrict__ Wv, unsigned short* __restrict__ wt) {
  __shared__ float t[64][65];
  const int kt = blockIdx.x, nt = blockIdx.y, wsel = blockIdx.z;
  const float* W = wsel == 0 ? Wq : (wsel == 1 ? Wk : Wv);
  const int lx = threadIdx.x & 63, ly = threadIdx.x >> 6;
  for (int i = 0; i < 64; i += 4)
    t[ly + i][lx] = W[(size_t)(kt * 64 + ly + i) * 768 + nt * 64 + lx];
  __syncthreads();
  for (int i = 0; i < 64; i += 4) {
    int r = ly + i;
    wt[((size_t)wsel * 768 + nt * 64 + r) * 768 + kt * 64 + lx] = f2bf(t[lx][r]);
  }
}

// ---------------- K1: fused QKV GEMM (bf16 MFMA) ----------------
__global__ __launch_bounds__(256) void k_qkv_gemm(
    const unsigned short* __restrict__ A,   // [2048][768] bf16
    const unsigned short* __restrict__ Bt,  // [2304][768] bf16 (row n, col k)
    const float* __restrict__ bq, const float* __restrict__ bk, const float* __restrict__ bv,
    unsigned short* __restrict__ qbf,       // [B][H][L][D]
    unsigned short* __restrict__ kbf,       // [B][H][L][D]
    unsigned short* __restrict__ vbt) {     // [B][H][D][L]
  __shared__ __align__(16) unsigned short lA[64 * 64];
  __shared__ __align__(16) unsigned short lB[64 * 64];
  const int tid = threadIdx.x, lane = tid & 63, w = tid >> 6;
  const int m0 = blockIdx.x * 64, n0 = blockIdx.y * 64;
  const int wm = (w >> 1) * 32, wn = (w & 1) * 32;
  f32x4 acc[2][2] = {};

  for (int kt = 0; kt < 12; ++kt) {
    __syncthreads();
#pragma unroll
    for (int i = 0; i < 2; ++i) {
      int e16 = i * 256 + tid;          // 16B unit, 0..511 (64 rows x 128B)
      int row = e16 >> 3;
      int kb = (e16 & 7) * 16;
      int dst = row * 128 + (kb ^ ((row & 7) << 4));   // XOR swizzle
      u32x4 va = *(const u32x4*)((const char*)A + (size_t)(m0 + row) * 1536 + kt * 128 + kb);
      *(u32x4*)((char*)lA + dst) = va;
      u32x4 vb = *(const u32x4*)((const char*)Bt + (size_t)(n0 + row) * 1536 + kt * 128 + kb);
      *(u32x4*)((char*)lB + dst) = vb;
    }
    __syncthreads();
#pragma unroll
    for (int ks = 0; ks < 2; ++ks) {
      bf16x8 fa[2], fb[2];
      const int kbyte = (ks * 32 + (lane >> 4) * 8) * 2;
#pragma unroll
      for (int mi = 0; mi < 2; ++mi) {
        int row = wm + mi * 16 + (lane & 15);
        fa[mi] = *(const bf16x8*)((const char*)lA + row * 128 + (kbyte ^ ((row & 7) << 4)));
      }
#pragma unroll
      for (int ni = 0; ni < 2; ++ni) {
        int row = wn + ni * 16 + (lane & 15);
        fb[ni] = *(const bf16x8*)((const char*)lB + row * 128 + (kbyte ^ ((row & 7) << 4)));
      }
#pragma unroll
      for (int mi = 0; mi < 2; ++mi)
#pragma unroll
        for (int ni = 0; ni < 2; ++ni)
          acc[mi][ni] = __builtin_amdgcn_mfma_f32_16x16x32_bf16(fa[mi], fb[ni], acc[mi][ni], 0, 0, 0);
    }
  }
#pragma unroll
  for (int mi = 0; mi < 2; ++mi)
#pragma unroll
    for (int ni = 0; ni < 2; ++ni) {
      int gn = n0 + wn + ni * 16 + (lane & 15);
      float bias = (gn < 768) ? bq[gn] : (gn < 1536 ? bk[gn - 768] : bv[gn - 1536]);
#pragma unroll
      for (int r = 0; r < 4; ++r) {
        int gm = m0 + wm + mi * 16 + ((lane >> 4) << 2) + r;
        float val = acc[mi][ni][r] + bias;
        int b = gm >> 9, l = gm & 511;
        int d = gn & 63;
        if (gn < 768) {
          int h = gn >> 6;
          qbf[(((size_t)(b * 12 + h)) * 512 + l) * 64 + d] = f2bf(val);
        } else if (gn < 1536) {
          int h = (gn - 768) >> 6;
          kbf[(((size_t)(b * 12 + h)) * 512 + l) * 64 + d] = f2bf(val);
        } else {
          int h = (gn - 1536) >> 6;
          vbt[(((size_t)(b * 12 + h)) * 64 + d) * 512 + l] = f2bf(val);
        }
      }
    }
}

// ---------------- K2a: content scores S = q.k^T per (b,h) via MFMA ----------------
__global__ __launch_bounds__(256) void k_scores(
    const unsigned short* __restrict__ qbf, const unsigned short* __restrict__ kbf,
    float* __restrict__ S) {
  __shared__ __align__(16) unsigned short lQ[64 * 64];
  __shared__ __align__(16) unsigned short lK[64 * 64];
  const int tid = threadIdx.x, lane = tid & 63, w = tid >> 6;
  const int mt = blockIdx.x, lt = blockIdx.y, bh = blockIdx.z;
  const int wm = (w >> 1) * 32, wn = (w & 1) * 32;
  f32x4 acc[2][2] = {};
#pragma unroll
  for (int i = 0; i < 2; ++i) {
    int e16 = i * 256 + tid;
    int row = e16 >> 3;
    int kb = (e16 & 7) * 16;
    int dst = row * 128 + (kb ^ ((row & 7) << 4));
    u32x4 vq = *(const u32x4*)((const char*)qbf + ((size_t)bh * 512 + lt * 64 + row) * 128 + kb);
    *(u32x4*)((char*)lQ + dst) = vq;
    u32x4 vk = *(const u32x4*)((const char*)kbf + ((size_t)bh * 512 + mt * 64 + row) * 128 + kb);
    *(u32x4*)((char*)lK + dst) = vk;
  }
  __syncthreads();
#pragma unroll
  for (int ks = 0; ks < 2; ++ks) {
    bf16x8 fa[2], fb[2];
    const int kbyte = (ks * 32 + (lane >> 4) * 8) * 2;
#pragma unroll
    for (int mi = 0; mi < 2; ++mi) {
      int row = wm + mi * 16 + (lane & 15);
      fa[mi] = *(const bf16x8*)((const char*)lQ + row * 128 + (kbyte ^ ((row & 7) << 4)));
    }
#pragma unroll
    for (int ni = 0; ni < 2; ++ni) {
      int row = wn + ni * 16 + (lane & 15);
      fb[ni] = *(const bf16x8*)((const char*)lK + row * 128 + (kbyte ^ ((row & 7) << 4)));
    }
#pragma unroll
    for (int mi = 0; mi < 2; ++mi)
#pragma unroll
      for (int ni = 0; ni < 2; ++ni)
        acc[mi][ni] = __builtin_amdgcn_mfma_f32_16x16x32_bf16(fa[mi], fb[ni], acc[mi][ni], 0, 0, 0);
  }
#pragma unroll
  for (int mi = 0; mi < 2; ++mi)
#pragma unroll
    for (int ni = 0; ni < 2; ++ni) {
      int gm = mt * 64 + wn + ni * 16 + (lane & 15);
#pragma unroll
      for (int r = 0; r < 4; ++r) {
        int gl = lt * 64 + wm + mi * 16 + ((lane >> 4) << 2) + r;
        S[(size_t)bh * 262144 + (size_t)gl * 512 + gm] = acc[mi][ni][r];
      }
    }
}

// ---------------- K2b: fused relation kernel, one block per (b,l) ----------------
// phase A: rel-K scores (dbuf-prefetched relk tiles), acc in registers
// phase B: +content, softmax (wave owns 3 heads), probs -> LDS bf16 + pbf global
// phase C: rel-V context (wave owns 128 r, lane owns d), LDS reduce -> crel
__global__ __launch_bounds__(256) void k_rel(
    const unsigned short* __restrict__ qbf,
    const float* __restrict__ relk,   // [B][L][L][D]  (b, l, r, d)
    const float* __restrict__ relv,   // [B][L][L][D]  indexed (b, r, l, d)
    const float* __restrict__ S,
    unsigned short* __restrict__ pbf,
    float* __restrict__ crel) {       // [B][L][768]
  __shared__ __align__(16) float qs[768];                 //  3 KB
  __shared__ __align__(16) unsigned short ps[12 * 512];   // 12 KB  probs bf16
  __shared__ __align__(16) char rk[2][16384];             // 32 KB  relk dbuf (swizzled)
  const int tid = threadIdx.x, lane = tid & 63, w = tid >> 6;
  const int bl = blockIdx.x;
  const int b = bl >> 9, l = bl & 511;

  for (int i = tid; i < 768; i += 256) {
    int h = i >> 6, d = i & 63;
    qs[i] = bf2f(qbf[(((size_t)(b * 12 + h)) * 512 + l) * 64 + d]);
  }

  const char* relk_base = (const char*)relk + (size_t)bl * 131072;
  // stage tile t into buffer buf: pre-swizzled global source, linear LDS dest
#define STAGE(t, buf)                                                        \
  {                                                                          \
    const char* gbase = relk_base + (t) * 16384;                             \
    _Pragma("unroll")                                                        \
    for (int i = 0; i < 4; ++i) {                                            \
      int slot = i * 256 + tid;                                              \
      int row = slot >> 4, x = slot & 15;                                    \
      const void* src = gbase + row * 256 + ((x * 16) ^ ((row & 7) << 4));   \
      gload_lds16(src, &rk[buf][(size_t)(i * 256 + w * 64) * 16]);           \
    }                                                                        \
  }

  float acc[3][8];
#pragma unroll
  for (int hh = 0; hh < 3; ++hh)
#pragma unroll
    for (int j = 0; j < 8; ++j) acc[hh][j] = 0.f;

  STAGE(0, 0);
  __syncthreads();   // tile0 + qs visible
#pragma unroll
  for (int t = 0; t < 8; ++t) {
    if (t < 7) STAGE(t + 1, (t + 1) & 1);     // async prefetch, overlaps compute
    // lane owns r = t*64+lane; wave owns heads 3w..3w+2
#pragma unroll 4
    for (int dc = 0; dc < 16; ++dc) {
      f32x4 rv = *(const f32x4*)(&rk[t & 1][0] + lane * 256 + ((dc * 16) ^ ((lane & 7) << 4)));
#pragma unroll
      for (int hh = 0; hh < 3; ++hh) {
        f32x4 q4 = *(const f32x4*)&qs[(w * 3 + hh) * 64 + dc * 4];
        acc[hh][t] += rv.x * q4.x + rv.y * q4.y + rv.z * q4.z + rv.w * q4.w;
      }
    }
    __syncthreads();   // drains prefetch (overlapped) + guards buffer reuse
  }
#undef STAGE

  // phase B: content add, scale, softmax; probs -> LDS bf16 + global pbf
#pragma unroll
  for (int hh = 0; hh < 3; ++hh) {
    int h = w * 3 + hh;
    size_t srow = (((size_t)(b * 12 + h)) * 512 + l) * 512;
    float mx = -1e30f;
#pragma unroll
    for (int j = 0; j < 8; ++j) {
      float s = (acc[hh][j] + S[srow + j * 64 + lane]) * 0.125f;
      acc[hh][j] = s;
      mx = fmaxf(mx, s);
    }
#pragma unroll
    for (int off = 32; off; off >>= 1) mx = fmaxf(mx, __shfl_xor(mx, off));
    float sm = 0.f;
#pragma unroll
    for (int j = 0; j < 8; ++j) { acc[hh][j] = __expf(acc[hh][j] - mx); sm += acc[hh][j]; }
#pragma unroll
    for (int off = 32; off; off >>= 1) sm += __shfl_xor(sm, off);
    float inv = 1.f / sm;
#pragma unroll
    for (int j = 0; j < 8; ++j) {
      unsigned short pb = f2bf(acc[hh][j] * inv);
      ps[h * 512 + j * 64 + lane] = pb;
      pbf[srow + j * 64 + lane] = pb;
    }
  }
  __syncthreads();

  // phase C: relation-V. wave w: r in [w*128, w*128+128); lane owns d.
  float cacc[12];
#pragma unroll
  for (int h = 0; h < 12; ++h) cacc[h] = 0.f;
  const float* vbase = relv + ((size_t)b * 512 * 512 + (size_t)l) * 64 + lane;
#pragma unroll 2
  for (int rc = 0; rc < 32; ++rc) {
    int r0 = w * 128 + rc * 4;
    float v0 = vbase[(size_t)(r0 + 0) * 32768];
    float v1 = vbase[(size_t)(r0 + 1) * 32768];
    float v2 = vbase[(size_t)(r0 + 2) * 32768];
    float v3 = vbase[(size_t)(r0 + 3) * 32768];
#pragma unroll
    for (int h = 0; h < 12; ++h) {
      ushort4 p4 = *(const ushort4*)&ps[h * 512 + r0];   // 8B wave-uniform LDS broadcast
      cacc[h] += bf2f(p4.x) * v0 + bf2f(p4.y) * v1 + bf2f(p4.z) * v2 + bf2f(p4.w) * v3;
    }
  }
  // cross-wave reduce in LDS (reuse rk space; dead after phase A)
  float* red = (float*)rk;
#pragma unroll
  for (int h = 0; h < 12; ++h) red[(w * 12 + h) * 64 + lane] = cacc[h];
  __syncthreads();
  for (int i = tid; i < 768; i += 256) {
    int h = i >> 6, d = i & 63;
    crel[(size_t)bl * 768 + i] =
        red[h * 64 + d] + red[(12 + h) * 64 + d] + red[(24 + h) * 64 + d] + red[(36 + h) * 64 + d];
  }
}

// ---------------- K3: ctx = P@V per (b,h) via MFMA, + crel, write out ----------------
__global__ __launch_bounds__(256) void k_pv(
    const unsigned short* __restrict__ pbf,   // [B][H][L][M]
    const unsigned short* __restrict__ vbt,   // [B][H][D][M]
    const float* __restrict__ crel,
    float* __restrict__ out) {
  __shared__ __align__(16) unsigned short lP[64 * 64];
  __shared__ __align__(16) unsigned short lV[64 * 64];
  const int tid = threadIdx.x, lane = tid & 63, w = tid >> 6;
  const int lt = blockIdx.x, bh = blockIdx.y;
  const int b = bh / 12, h = bh % 12;
  const int wm = (w >> 1) * 32, wn = (w & 1) * 32;
  f32x4 acc[2][2] = {};
  const char* pbase = (const char*)pbf + ((size_t)bh * 512 + lt * 64) * 1024;
  const char* vbase = (const char*)vbt + (size_t)bh * 64 * 1024;
  for (int kt = 0; kt < 8; ++kt) {
    __syncthreads();
#pragma unroll
    for (int i = 0; i < 2; ++i) {
      int e16 = i * 256 + tid;
      int row = e16 >> 3;
      int kb = (e16 & 7) * 16;
      int dst = row * 128 + (kb ^ ((row & 7) << 4));
      u32x4 vp = *(const u32x4*)(pbase + (size_t)row * 1024 + kt * 128 + kb);
      *(u32x4*)((char*)lP + dst) = vp;
      u32x4 vv = *(const u32x4*)(vbase + (size_t)row * 1024 + kt * 128 + kb);
      *(u32x4*)((char*)lV + dst) = vv;
    }
    __syncthreads();
#pragma unroll
    for (int ks = 0; ks < 2; ++ks) {
      bf16x8 fa[2], fb[2];
      const int kbyte = (ks * 32 + (lane >> 4) * 8) * 2;
#pragma unroll
      for (int mi = 0; mi < 2; ++mi) {
        int row = wm + mi * 16 + (lane & 15);
        fa[mi] = *(const bf16x8*)((const char*)lP + row * 128 + (kbyte ^ ((row & 7) << 4)));
      }
#pragma unroll
      for (int ni = 0; ni < 2; ++ni) {
        int row = wn + ni * 16 + (lane & 15);
        fb[ni] = *(const bf16x8*)((const char*)lV + row * 128 + (kbyte ^ ((row & 7) << 4)));
      }
#pragma unroll
      for (int mi = 0; mi < 2; ++mi)
#pragma unroll
        for (int ni = 0; ni < 2; ++ni)
          acc[mi][ni] = __builtin_amdgcn_mfma_f32_16x16x32_bf16(fa[mi], fb[ni], acc[mi][ni], 0, 0, 0);
    }
  }
#pragma unroll
  for (int mi = 0; mi < 2; ++mi)
#pragma unroll
    for (int ni = 0; ni < 2; ++ni) {
      int gd = wn + ni * 16 + (lane & 15);
#pragma unroll
      for (int r = 0; r < 4; ++r) {
        int gl = lt * 64 + wm + mi * 16 + ((lane >> 4) << 2) + r;
        size_t o = ((size_t)b * 512 + gl) * 768 + h * 64 + gd;
        out[o] = acc[mi][ni][r] + crel[o];
      }
    }
}

extern "C" void kernel_launch(void* const* d_in, const int* in_sizes, int n_in,
                              void* d_out, int out_size, void* d_ws, size_t ws_size,
                              hipStream_t stream) {
  (void)in_sizes; (void)n_in; (void)out_size; (void)ws_size;
  const float* hidden = (const float*)d_in[0];
  const float* relk   = (const float*)d_in[1];
  const float* relv   = (const float*)d_in[2];
  const float* Wq     = (const float*)d_in[3];
  const float* bq     = (const float*)d_in[4];
  const float* Wk     = (const float*)d_in[5];
  const float* bk     = (const float*)d_in[6];
  const float* Wv     = (const float*)d_in[7];
  const float* bv     = (const float*)d_in[8];
  float* out = (float*)d_out;
  char* ws = (char*)d_ws;

  unsigned short* hb  = (unsigned short*)(ws);
  unsigned short* wt  = (unsigned short*)(ws + 3145728);
  unsigned short* qbf = (unsigned short*)(ws + 6684672);
  unsigned short* kbf = (unsigned short*)(ws + 9830400);
  unsigned short* vbt = (unsigned short*)(ws + 12976128);
  float*          S   = (float*)(ws + 16121856);
  unsigned short* pbf = (unsigned short*)(ws + 66453504);
  float*          cr  = (float*)(ws + 91619328);
  // end: 97,910,784 bytes

  k_cvt_hidden<<<1536, 256, 0, stream>>>(hidden, hb);
  k_transp_w<<<dim3(12, 12, 3), 256, 0, stream>>>(Wq, Wk, Wv, wt);
  k_qkv_gemm<<<dim3(32, 36), 256, 0, stream>>>(hb, wt, bq, bk, bv, qbf, kbf, vbt);
  k_scores<<<dim3(8, 8, 48), 256, 0, stream>>>(qbf, kbf, S);
  k_rel<<<2048, 256, 0, stream>>>(qbf, relk, relv, S, pbf, cr);
  k_pv<<<dim3(8, 48), 256, 0, stream>>>(pbf, vbt, cr, out);
}

// Round 4
// 189.137 us; speedup vs baseline: 1.1927x; 1.0577x over previous
//
#include <hip/hip_runtime.h>
#include <stdint.h>

// BertSelfAttentionWithRelation  B=4 L=512 H=12 D=64 HIDDEN=768
// Round 4: MFMA-ized k_rel.
//   phase A: scores_rel = q @ relk^T per (b,l) via mfma_16x16x32_bf16,
//            relk reg-staged f32->bf16 into dbuf LDS (T14 issue-early/write-late)
//   phase B: softmax (wave owns 3 heads) using S_rel (LDS) + S content (global)
//   phase C: ctx_rel^T = relv^T @ P^T via MFMA; relv staged TRANSPOSED vt[d][r]
//   barriers: lgkmcnt(0)+s_barrier only (no vmcnt drain -> prefetch survives)
//   ws layout unchanged (~97.9 MB)

typedef __attribute__((ext_vector_type(8))) short bf16x8;
typedef __attribute__((ext_vector_type(4))) float f32x4;
typedef __attribute__((ext_vector_type(4))) unsigned int u32x4;
typedef __attribute__((ext_vector_type(2))) unsigned int u32x2;

__device__ __forceinline__ unsigned short f2bf(float f) {
  union { float f; unsigned int u; } v; v.f = f;
  unsigned int r = v.u + 0x7fffu + ((v.u >> 16) & 1u);
  return (unsigned short)(r >> 16);
}
__device__ __forceinline__ float bf2f(unsigned short s) {
  union { unsigned int u; float f; } v; v.u = ((unsigned int)s) << 16;
  return v.f;
}
// LDS-only barrier: make our ds_writes visible without draining vmcnt
// (in-flight global->reg prefetch loads survive the barrier)
__device__ __forceinline__ void lds_barrier() {
  asm volatile("s_waitcnt lgkmcnt(0)\ns_barrier" ::: "memory");
}

// ---------------- K0a: hidden fp32 -> bf16 ----------------
__global__ void k_cvt_hidden(const float* __restrict__ x, unsigned short* __restrict__ y) {
  int i = blockIdx.x * 256 + threadIdx.x;
  float4 v = reinterpret_cast<const float4*>(x)[i];
  ushort4 o;
  o.x = f2bf(v.x); o.y = f2bf(v.y); o.z = f2bf(v.z); o.w = f2bf(v.w);
  reinterpret_cast<ushort4*>(y)[i] = o;
}

// ---------------- K0b: W -> W^T concat bf16 ----------------
__global__ void k_transp_w(const float* __restrict__ Wq, const float* __restrict__ Wk,
                           const float* __restrict__ Wv, unsigned short* __restrict__ wt) {
  __shared__ float t[64][65];
  const int kt = blockIdx.x, nt = blockIdx.y, wsel = blockIdx.z;
  const float* W = wsel == 0 ? Wq : (wsel == 1 ? Wk : Wv);
  const int lx = threadIdx.x & 63, ly = threadIdx.x >> 6;
  for (int i = 0; i < 64; i += 4)
    t[ly + i][lx] = W[(size_t)(kt * 64 + ly + i) * 768 + nt * 64 + lx];
  __syncthreads();
  for (int i = 0; i < 64; i += 4) {
    int r = ly + i;
    wt[((size_t)wsel * 768 + nt * 64 + r) * 768 + kt * 64 + lx] = f2bf(t[lx][r]);
  }
}

// ---------------- K1: fused QKV GEMM (bf16 MFMA) ----------------
__global__ __launch_bounds__(256) void k_qkv_gemm(
    const unsigned short* __restrict__ A, const unsigned short* __restrict__ Bt,
    const float* __restrict__ bq, const float* __restrict__ bk, const float* __restrict__ bv,
    unsigned short* __restrict__ qbf, unsigned short* __restrict__ kbf,
    unsigned short* __restrict__ vbt) {
  __shared__ __align__(16) unsigned short lA[64 * 64];
  __shared__ __align__(16) unsigned short lB[64 * 64];
  const int tid = threadIdx.x, lane = tid & 63, w = tid >> 6;
  const int m0 = blockIdx.x * 64, n0 = blockIdx.y * 64;
  const int wm = (w >> 1) * 32, wn = (w & 1) * 32;
  f32x4 acc[2][2] = {};

  for (int kt = 0; kt < 12; ++kt) {
    __syncthreads();
#pragma unroll
    for (int i = 0; i < 2; ++i) {
      int e16 = i * 256 + tid;
      int row = e16 >> 3;
      int kb = (e16 & 7) * 16;
      int dst = row * 128 + (kb ^ ((row & 7) << 4));
      u32x4 va = *(const u32x4*)((const char*)A + (size_t)(m0 + row) * 1536 + kt * 128 + kb);
      *(u32x4*)((char*)lA + dst) = va;
      u32x4 vb = *(const u32x4*)((const char*)Bt + (size_t)(n0 + row) * 1536 + kt * 128 + kb);
      *(u32x4*)((char*)lB + dst) = vb;
    }
    __syncthreads();
#pragma unroll
    for (int ks = 0; ks < 2; ++ks) {
      bf16x8 fa[2], fb[2];
      const int kbyte = (ks * 32 + (lane >> 4) * 8) * 2;
#pragma unroll
      for (int mi = 0; mi < 2; ++mi) {
        int row = wm + mi * 16 + (lane & 15);
        fa[mi] = *(const bf16x8*)((const char*)lA + row * 128 + (kbyte ^ ((row & 7) << 4)));
      }
#pragma unroll
      for (int ni = 0; ni < 2; ++ni) {
        int row = wn + ni * 16 + (lane & 15);
        fb[ni] = *(const bf16x8*)((const char*)lB + row * 128 + (kbyte ^ ((row & 7) << 4)));
      }
#pragma unroll
      for (int mi = 0; mi < 2; ++mi)
#pragma unroll
        for (int ni = 0; ni < 2; ++ni)
          acc[mi][ni] = __builtin_amdgcn_mfma_f32_16x16x32_bf16(fa[mi], fb[ni], acc[mi][ni], 0, 0, 0);
    }
  }
#pragma unroll
  for (int mi = 0; mi < 2; ++mi)
#pragma unroll
    for (int ni = 0; ni < 2; ++ni) {
      int gn = n0 + wn + ni * 16 + (lane & 15);
      float bias = (gn < 768) ? bq[gn] : (gn < 1536 ? bk[gn - 768] : bv[gn - 1536]);
#pragma unroll
      for (int r = 0; r < 4; ++r) {
        int gm = m0 + wm + mi * 16 + ((lane >> 4) << 2) + r;
        float val = acc[mi][ni][r] + bias;
        int b = gm >> 9, l = gm & 511;
        int d = gn & 63;
        if (gn < 768) {
          int h = gn >> 6;
          qbf[(((size_t)(b * 12 + h)) * 512 + l) * 64 + d] = f2bf(val);
        } else if (gn < 1536) {
          int h = (gn - 768) >> 6;
          kbf[(((size_t)(b * 12 + h)) * 512 + l) * 64 + d] = f2bf(val);
        } else {
          int h = (gn - 1536) >> 6;
          vbt[(((size_t)(b * 12 + h)) * 64 + d) * 512 + l] = f2bf(val);
        }
      }
    }
}

// ---------------- K2a: content scores S = q.k^T per (b,h) ----------------
__global__ __launch_bounds__(256) void k_scores(
    const unsigned short* __restrict__ qbf, const unsigned short* __restrict__ kbf,
    float* __restrict__ S) {
  __shared__ __align__(16) unsigned short lQ[64 * 64];
  __shared__ __align__(16) unsigned short lK[64 * 64];
  const int tid = threadIdx.x, lane = tid & 63, w = tid >> 6;
  const int mt = blockIdx.x, lt = blockIdx.y, bh = blockIdx.z;
  const int wm = (w >> 1) * 32, wn = (w & 1) * 32;
  f32x4 acc[2][2] = {};
#pragma unroll
  for (int i = 0; i < 2; ++i) {
    int e16 = i * 256 + tid;
    int row = e16 >> 3;
    int kb = (e16 & 7) * 16;
    int dst = row * 128 + (kb ^ ((row & 7) << 4));
    u32x4 vq = *(const u32x4*)((const char*)qbf + ((size_t)bh * 512 + lt * 64 + row) * 128 + kb);
    *(u32x4*)((char*)lQ + dst) = vq;
    u32x4 vk = *(const u32x4*)((const char*)kbf + ((size_t)bh * 512 + mt * 64 + row) * 128 + kb);
    *(u32x4*)((char*)lK + dst) = vk;
  }
  __syncthreads();
#pragma unroll
  for (int ks = 0; ks < 2; ++ks) {
    bf16x8 fa[2], fb[2];
    const int kbyte = (ks * 32 + (lane >> 4) * 8) * 2;
#pragma unroll
    for (int mi = 0; mi < 2; ++mi) {
      int row = wm + mi * 16 + (lane & 15);
      fa[mi] = *(const bf16x8*)((const char*)lQ + row * 128 + (kbyte ^ ((row & 7) << 4)));
    }
#pragma unroll
    for (int ni = 0; ni < 2; ++ni) {
      int row = wn + ni * 16 + (lane & 15);
      fb[ni] = *(const bf16x8*)((const char*)lK + row * 128 + (kbyte ^ ((row & 7) << 4)));
    }
#pragma unroll
    for (int mi = 0; mi < 2; ++mi)
#pragma unroll
      for (int ni = 0; ni < 2; ++ni)
        acc[mi][ni] = __builtin_amdgcn_mfma_f32_16x16x32_bf16(fa[mi], fb[ni], acc[mi][ni], 0, 0, 0);
  }
#pragma unroll
  for (int mi = 0; mi < 2; ++mi)
#pragma unroll
    for (int ni = 0; ni < 2; ++ni) {
      int gm = mt * 64 + wn + ni * 16 + (lane & 15);
#pragma unroll
      for (int r = 0; r < 4; ++r) {
        int gl = lt * 64 + wm + mi * 16 + ((lane >> 4) << 2) + r;
        S[(size_t)bh * 262144 + (size_t)gl * 512 + gm] = acc[mi][ni][r];
      }
    }
}

// ---------------- K2b: fused relation kernel (MFMA), one block per (b,l) ----
__global__ __launch_bounds__(256, 3) void k_rel(
    const unsigned short* __restrict__ qbf,
    const float* __restrict__ relk,   // [B][L][L][D]  (b, l, r, d)
    const float* __restrict__ relv,   // [B][L][L][D]  indexed (b, r, l, d)
    const float* __restrict__ S,
    unsigned short* __restrict__ pbf,
    float* __restrict__ crel) {
  // region X (32 KB): phase A rk dbuf (2x16K) -> phase B S_rel[12][512]f32 (24K)
  //                   -> phase C vt dbuf (2x16K)
  __shared__ __align__(16) char X[32768];
  __shared__ __align__(16) unsigned short ps[16 * 512];   // 16 KB probs bf16
  const int tid = threadIdx.x, lane = tid & 63, w = tid >> 6;
  const int bl = blockIdx.x, b = bl >> 9, l = bl & 511;
  const int lm = lane & 15, lg = lane >> 4;
  const int rr = tid >> 4, xc = tid & 15;   // staging: row-base / 16B-column

  // zero ps rows 12..15 (MFMA operand padding)
  {
    u32x4 zz = {0u, 0u, 0u, 0u};
    *(u32x4*)((char*)ps + 12288 + tid * 16) = zz;
  }

  // q A-fragments: row h=lm (clamped), k-octet d = ks*32 + lg*8
  const int hq = lm < 12 ? lm : 11;
  const char* qrow = (const char*)qbf + (((size_t)b * 12 + hq) * 512 + l) * 128;
  const bf16x8 qa0 = *(const bf16x8*)(qrow + lg * 16);
  const bf16x8 qa1 = *(const bf16x8*)(qrow + 64 + lg * 16);

  const char* rkbase = (const char*)relk + (size_t)bl * 131072;
  const char* rvbase = (const char*)relv + (size_t)b * 67108864 + (size_t)l * 256;

  f32x4 stg[2][8];
  f32x4 accA[4][2];
#pragma unroll
  for (int t = 0; t < 4; ++t) {
    accA[t][0] = {0.f, 0.f, 0.f, 0.f};
    accA[t][1] = {0.f, 0.f, 0.f, 0.f};
  }

  // ---- phase A: rel-K scores via MFMA, 4 r-tiles of 128 ----
#pragma unroll
  for (int i = 0; i < 8; ++i)
    stg[0][i] = *(const f32x4*)(rkbase + (size_t)(i * 16 + rr) * 256 + xc * 16);

#pragma unroll
  for (int t = 0; t < 4; ++t) {
    if (t < 3) {
#pragma unroll
      for (int i = 0; i < 8; ++i)
        stg[(t + 1) & 1][i] =
            *(const f32x4*)(rkbase + (size_t)((t + 1) * 128 + i * 16 + rr) * 256 + xc * 16);
    }
    char* buf = X + (t & 1) * 16384;   // [128 r][64 d] bf16, XOR-swizzled rows
#pragma unroll
    for (int i = 0; i < 8; ++i) {
      const int rl = i * 16 + rr;
      f32x4 v = stg[t & 1][i];
      u32x2 pk;
      pk.x = (unsigned)f2bf(v[0]) | ((unsigned)f2bf(v[1]) << 16);
      pk.y = (unsigned)f2bf(v[2]) | ((unsigned)f2bf(v[3]) << 16);
      *(u32x2*)(buf + rl * 128 + ((xc * 8) ^ ((rl & 7) << 4))) = pk;
    }
    lds_barrier();
#pragma unroll
    for (int p = 0; p < 2; ++p) {
      const int rrow = (w * 2 + p) * 16 + lm;
      const char* base = buf + rrow * 128;
      bf16x8 fb0 = *(const bf16x8*)(base + ((lg * 16) ^ ((rrow & 7) << 4)));
      bf16x8 fb1 = *(const bf16x8*)(base + ((64 + lg * 16) ^ ((rrow & 7) << 4)));
      accA[t][p] = __builtin_amdgcn_mfma_f32_16x16x32_bf16(qa0, fb0, accA[t][p], 0, 0, 0);
      accA[t][p] = __builtin_amdgcn_mfma_f32_16x16x32_bf16(qa1, fb1, accA[t][p], 0, 0, 0);
    }
  }

  // prefetch content scores into regs (overlaps S_rel staging)
  float sreg[3][8];
#pragma unroll
  for (int hh = 0; hh < 3; ++hh) {
    const float* sp = S + (((size_t)b * 12 + (w * 3 + hh)) * 512 + l) * 512 + lane;
#pragma unroll
    for (int j = 0; j < 8; ++j) sreg[hh][j] = sp[j * 64];
  }

  lds_barrier();   // all phase-A MFMA reads done -> X reusable
  // S_rel[12][512] f32 into X, swizzled rows
  if (lg < 3) {
#pragma unroll
    for (int t = 0; t < 4; ++t)
#pragma unroll
      for (int p = 0; p < 2; ++p) {
        const int r = t * 128 + w * 32 + p * 16 + lm;
#pragma unroll
        for (int reg = 0; reg < 4; ++reg) {
          const int h = lg * 4 + reg;
          *(float*)(X + h * 2048 + ((r * 4) ^ ((h & 7) << 4))) = accA[t][p][reg];
        }
      }
  }
  lds_barrier();   // S_rel visible

  // phase-C tile-0 prefetch (overlaps softmax)
#pragma unroll
  for (int i = 0; i < 8; ++i)
    stg[0][i] = *(const f32x4*)(rvbase + (size_t)(i * 16 + rr) * 131072 + xc * 16);

  // ---- phase B: softmax; wave owns heads 3w..3w+2, lane owns r=j*64+lane ----
#pragma unroll
  for (int hh = 0; hh < 3; ++hh) {
    const int h = w * 3 + hh;
    const size_t srow = (((size_t)b * 12 + h) * 512 + l) * 512;
    float sv[8];
    float mx = -1e30f;
#pragma unroll
    for (int j = 0; j < 8; ++j) {
      const int r = j * 64 + lane;
      float sr = *(const float*)(X + h * 2048 + ((r * 4) ^ ((h & 7) << 4)));
      float s = (sr + sreg[hh][j]) * 0.125f;
      sv[j] = s;
      mx = fmaxf(mx, s);
    }
#pragma unroll
    for (int off = 32; off; off >>= 1) mx = fmaxf(mx, __shfl_xor(mx, off));
    float sm = 0.f;
#pragma unroll
    for (int j = 0; j < 8; ++j) { sv[j] = __expf(sv[j] - mx); sm += sv[j]; }
#pragma unroll
    for (int off = 32; off; off >>= 1) sm += __shfl_xor(sm, off);
    const float inv = 1.f / sm;
#pragma unroll
    for (int j = 0; j < 8; ++j) {
      const int r = j * 64 + lane;
      const unsigned short pb = f2bf(sv[j] * inv);
      *(unsigned short*)((char*)ps + h * 1024 + ((r * 2) ^ ((h & 7) << 4))) = pb;
      pbf[srow + r] = pb;
    }
  }
  lds_barrier();   // ps visible; S_rel dead -> X reusable

  // ---- phase C: ctx_rel^T = relv^T @ P^T via MFMA; vt[d][r] transposed ----
  f32x4 accC = {0.f, 0.f, 0.f, 0.f};
#pragma unroll
  for (int t = 0; t < 4; ++t) {
    if (t < 3) {
#pragma unroll
      for (int i = 0; i < 8; ++i)
        stg[(t + 1) & 1][i] =
            *(const f32x4*)(rvbase + (size_t)((t + 1) * 128 + i * 16 + rr) * 131072 + xc * 16);
    }
    char* buf = X + (t & 1) * 16384;   // vt [64 d][128 r] bf16, swz16 rows
#pragma unroll
    for (int i = 0; i < 8; ++i) {
      const int rl = i * 16 + rr;
      f32x4 v = stg[t & 1][i];
#pragma unroll
      for (int e = 0; e < 4; ++e) {
        const int d = xc * 4 + e;
        *(unsigned short*)(buf + d * 256 + ((rl * 2) ^ ((d & 15) << 4))) = f2bf(v[e]);
      }
    }
    lds_barrier();
    const int drow = w * 16 + lm;
    const char* abase = buf + drow * 256;
#pragma unroll
    for (int kk = 0; kk < 4; ++kk) {
      bf16x8 fa = *(const bf16x8*)(abase + (((kk * 32 + lg * 8) * 2) ^ ((drow & 15) << 4)));
      const int rg = t * 128 + kk * 32 + lg * 8;
      bf16x8 fp = *(const bf16x8*)((const char*)ps + lm * 1024 + ((rg * 2) ^ ((lm & 7) << 4)));
      accC = __builtin_amdgcn_mfma_f32_16x16x32_bf16(fa, fp, accC, 0, 0, 0);
    }
  }
  // C[m=d-sub][n=h]: lane holds h=lm, d = w*16 + lg*4 + reg
  if (lm < 12) {
#pragma unroll
    for (int reg = 0; reg < 4; ++reg)
      crel[(size_t)bl * 768 + lm * 64 + w * 16 + lg * 4 + reg] = accC[reg];
  }
}

// ---------------- K3: ctx = P@V per (b,h) via MFMA, + crel ----------------
__global__ __launch_bounds__(256) void k_pv(
    const unsigned short* __restrict__ pbf, const unsigned short* __restrict__ vbt,
    const float* __restrict__ crel, float* __restrict__ out) {
  __shared__ __align__(16) unsigned short lP[64 * 64];
  __shared__ __align__(16) unsigned short lV[64 * 64];
  const int tid = threadIdx.x, lane = tid & 63, w = tid >> 6;
  const int lt = blockIdx.x, bh = blockIdx.y;
  const int b = bh / 12, h = bh % 12;
  const int wm = (w >> 1) * 32, wn = (w & 1) * 32;
  f32x4 acc[2][2] = {};
  const char* pbase = (const char*)pbf + ((size_t)bh * 512 + lt * 64) * 1024;
  const char* vbase = (const char*)vbt + (size_t)bh * 64 * 1024;
  for (int kt = 0; kt < 8; ++kt) {
    __syncthreads();
#pragma unroll
    for (int i = 0; i < 2; ++i) {
      int e16 = i * 256 + tid;
      int row = e16 >> 3;
      int kb = (e16 & 7) * 16;
      int dst = row * 128 + (kb ^ ((row & 7) << 4));
      u32x4 vp = *(const u32x4*)(pbase + (size_t)row * 1024 + kt * 128 + kb);
      *(u32x4*)((char*)lP + dst) = vp;
      u32x4 vv = *(const u32x4*)(vbase + (size_t)row * 1024 + kt * 128 + kb);
      *(u32x4*)((char*)lV + dst) = vv;
    }
    __syncthreads();
#pragma unroll
    for (int ks = 0; ks < 2; ++ks) {
      bf16x8 fa[2], fb[2];
      const int kbyte = (ks * 32 + (lane >> 4) * 8) * 2;
#pragma unroll
      for (int mi = 0; mi < 2; ++mi) {
        int row = wm + mi * 16 + (lane & 15);
        fa[mi] = *(const bf16x8*)((const char*)lP + row * 128 + (kbyte ^ ((row & 7) << 4)));
      }
#pragma unroll
      for (int ni = 0; ni < 2; ++ni) {
        int row = wn + ni * 16 + (lane & 15);
        fb[ni] = *(const bf16x8*)((const char*)lV + row * 128 + (kbyte ^ ((row & 7) << 4)));
      }
#pragma unroll
      for (int mi = 0; mi < 2; ++mi)
#pragma unroll
        for (int ni = 0; ni < 2; ++ni)
          acc[mi][ni] = __builtin_amdgcn_mfma_f32_16x16x32_bf16(fa[mi], fb[ni], acc[mi][ni], 0, 0, 0);
    }
  }
#pragma unroll
  for (int mi = 0; mi < 2; ++mi)
#pragma unroll
    for (int ni = 0; ni < 2; ++ni) {
      int gd = wn + ni * 16 + (lane & 15);
#pragma unroll
      for (int r = 0; r < 4; ++r) {
        int gl = lt * 64 + wm + mi * 16 + ((lane >> 4) << 2) + r;
        size_t o = ((size_t)b * 512 + gl) * 768 + h * 64 + gd;
        out[o] = acc[mi][ni][r] + crel[o];
      }
    }
}

extern "C" void kernel_launch(void* const* d_in, const int* in_sizes, int n_in,
                              void* d_out, int out_size, void* d_ws, size_t ws_size,
                              hipStream_t stream) {
  (void)in_sizes; (void)n_in; (void)out_size; (void)ws_size;
  const float* hidden = (const float*)d_in[0];
  const float* relk   = (const float*)d_in[1];
  const float* relv   = (const float*)d_in[2];
  const float* Wq     = (const float*)d_in[3];
  const float* bq     = (const float*)d_in[4];
  const float* Wk     = (const float*)d_in[5];
  const float* bk     = (const float*)d_in[6];
  const float* Wv     = (const float*)d_in[7];
  const float* bv     = (const float*)d_in[8];
  float* out = (float*)d_out;
  char* ws = (char*)d_ws;

  unsigned short* hb  = (unsigned short*)(ws);
  unsigned short* wt  = (unsigned short*)(ws + 3145728);
  unsigned short* qbf = (unsigned short*)(ws + 6684672);
  unsigned short* kbf = (unsigned short*)(ws + 9830400);
  unsigned short* vbt = (unsigned short*)(ws + 12976128);
  float*          S   = (float*)(ws + 16121856);
  unsigned short* pbf = (unsigned short*)(ws + 66453504);
  float*          cr  = (float*)(ws + 91619328);

  k_cvt_hidden<<<1536, 256, 0, stream>>>(hidden, hb);
  k_transp_w<<<dim3(12, 12, 3), 256, 0, stream>>>(Wq, Wk, Wv, wt);
  k_qkv_gemm<<<dim3(32, 36), 256, 0, stream>>>(hb, wt, bq, bk, bv, qbf, kbf, vbt);
  k_scores<<<dim3(8, 8, 48), 256, 0, stream>>>(qbf, kbf, S);
  k_rel<<<2048, 256, 0, stream>>>(qbf, relk, relv, S, pbf, cr);
  k_pv<<<dim3(8, 48), 256, 0, stream>>>(pbf, vbt, cr, out);
}